// Round 1
// baseline (1797.100 us; speedup 1.0000x reference)
//
#include <hip/hip_runtime.h>
#include <math.h>

namespace {

constexpr int kB = 32;
constexpr int kN = 19;
constexpr int kT = 2048;
constexpr int kD = 128;

constexpr int TILES = 32;          // (b,t) tiles per block; 2048/32=64 blocks per b -> never crosses b
constexpr int TPT   = 10;          // threads per tile: upper-tri blocks of a 4x4 grid of 5x5
constexpr int BDIM  = TILES * TPT; // 320 threads = 5 waves
constexpr int KC    = 16;          // k-chunk depth (d's per staging round)
constexpr int RPAD  = 20;          // padded row length in floats (16 data + 4 pad; also G row pitch)
constexpr int NROW  = 20;          // padded row count per tile (19 + 1)
constexpr int TSTR  = NROW * RPAD; // 400 floats per tile

constexpr float kTempInv = 10.0f;  // 1/TEMPERATURE
constexpr float kThresh  = 1e-4f;

__global__ __launch_bounds__(BDIM, 4)
void fused_graph_kernel(const float* __restrict__ feat, float* __restrict__ out)
{
    // 51200 B: staging buffer for k-chunks, then re-used as G / P matrix storage
    __shared__ float sBuf[TILES * TSTR];
    // 2560 B: per-tile inverse norms
    __shared__ float sInv[TILES * 20];

    const int tid = threadIdx.x;
    const int tl  = tid / TPT;        // tile-local index 0..31
    const int sub = tid - tl * TPT;   // 0..9 -> (bi,bj), bi<=bj in 4x4 block grid
    // triangle mapping without arrays (avoid scratch):
    // row starts {0,4,7,9}
    const int bi    = (sub >= 4) + (sub >= 7) + (sub >= 9);
    const int start = bi * 4 - (bi * (bi - 1)) / 2;
    const int bj    = bi + (sub - start);

    const int gt0 = blockIdx.x * TILES;      // global tile base = b*T + t
    const int b0  = gt0 >> 11;               // /2048
    const int t0  = gt0 & (kT - 1);
    const float* fb = feat + ((size_t)b0 * kN * kT + (size_t)t0) * kD;

    float acc[5][5];
#pragma unroll
    for (int r = 0; r < 5; ++r)
#pragma unroll
        for (int c = 0; c < 5; ++c) acc[r][c] = 0.f;

    // ================= Phase A: k-chunked staging + 5x5 register-blocked Gram =================
    for (int kc = 0; kc < kD; kc += KC) {
        // stage: 32 tiles x 20 rows x 4 float4  (2560 float4s, exactly 8 per thread)
#pragma unroll
        for (int it = 0; it < (TILES * NROW * (KC / 4)) / BDIM; ++it) {
            int q  = tid + it * BDIM;
            int tt = q / (NROW * (KC / 4));            // /80
            int rr = q - tt * (NROW * (KC / 4));
            int n  = rr >> 2;
            int d4 = rr & 3;
            float4 v = make_float4(0.f, 0.f, 0.f, 0.f);
            if (n < kN)
                v = *(const float4*)(fb + (size_t)n * (kT * kD) + (size_t)tt * kD + kc + d4 * 4);
            *(float4*)(&sBuf[tt * TSTR + n * RPAD + d4 * 4]) = v;
        }
        __syncthreads();

        const float* base = &sBuf[tl * TSTR];
#pragma unroll
        for (int s0 = 0; s0 < 4; ++s0) {
            // stagger d-chunk order by sub to spread LDS bank-group classes
            const int s = (s0 + sub) & 3;
            float4 ra[5], cb[5];
#pragma unroll
            for (int r = 0; r < 5; ++r)
                ra[r] = *(const float4*)(base + (bi * 5 + r) * RPAD + s * 4);
            if (bi == bj) {
#pragma unroll
                for (int c = 0; c < 5; ++c) cb[c] = ra[c];
            } else {
#pragma unroll
                for (int c = 0; c < 5; ++c)
                    cb[c] = *(const float4*)(base + (bj * 5 + c) * RPAD + s * 4);
            }
#pragma unroll
            for (int r = 0; r < 5; ++r)
#pragma unroll
                for (int c = 0; c < 5; ++c) {
                    acc[r][c] = fmaf(ra[r].x, cb[c].x, acc[r][c]);
                    acc[r][c] = fmaf(ra[r].y, cb[c].y, acc[r][c]);
                    acc[r][c] = fmaf(ra[r].z, cb[c].z, acc[r][c]);
                    acc[r][c] = fmaf(ra[r].w, cb[c].w, acc[r][c]);
                }
        }
        __syncthreads();
    }

    // ================= Phase A2: scatter raw Gram into LDS (with symmetric mirror) =============
    {
        float* g = &sBuf[tl * TSTR];
#pragma unroll
        for (int r = 0; r < 5; ++r) {
            const int i = bi * 5 + r;
#pragma unroll
            for (int c = 0; c < 5; ++c) {
                const int j = bj * 5 + c;
                if (i < kN && j < kN) {
                    g[i * RPAD + j] = acc[r][c];
                    if (i != j) g[j * RPAD + i] = acc[r][c];
                }
            }
        }
    }
    __syncthreads();

    // ================= Phase B1: inverse norms from Gram diagonal ==============================
    for (int q = tid; q < TILES * kN; q += BDIM) {
        const int tt = q / kN;
        const int i  = q - tt * kN;
        const float nrm = sqrtf(sBuf[tt * TSTR + i * RPAD + i]);
        sInv[tt * 20 + i] = 1.0f / fmaxf(nrm, 1e-12f);
    }
    __syncthreads();

    // ================= Phase B2: per-row softmax + exact top-3 + threshold (in place) ==========
    for (int q = tid; q < TILES * kN; q += BDIM) {
        const int tt = q / kN;
        const int i  = q - tt * kN;
        float* row = &sBuf[tt * TSTR + i * RPAD];
        const float* invp = &sInv[tt * 20];
        const float si = invp[i] * kTempInv;

        float l[kN];
        float m = -3.0e38f;
#pragma unroll
        for (int j = 0; j < kN; ++j) {
            const float g = row[j] * si * invp[j];
            l[j] = g;
            m = fmaxf(m, g);
        }
        float ssum = 0.f;
#pragma unroll
        for (int j = 0; j < kN; ++j) {
            const float e = __expf(l[j] - m);
            l[j] = e;
            ssum += e;
        }
        const float rs = 1.0f / ssum;
#pragma unroll
        for (int j = 0; j < kN; ++j) l[j] *= rs;

        // top-3 with lax.top_k tie semantics (strict > keeps lowest index on ties)
        int k1 = 0; float v1 = -1.f;
#pragma unroll
        for (int j = 0; j < kN; ++j) if (l[j] > v1) { v1 = l[j]; k1 = j; }
        int k2 = -1; float v2 = -1.f;
#pragma unroll
        for (int j = 0; j < kN; ++j) if (j != k1 && l[j] > v2) { v2 = l[j]; k2 = j; }
        int k3 = -1; float v3 = -1.f;
#pragma unroll
        for (int j = 0; j < kN; ++j) if (j != k1 && j != k2 && l[j] > v3) { v3 = l[j]; k3 = j; }

#pragma unroll
        for (int j = 0; j < kN; ++j) {
            const float p = l[j];
            const bool keep = (j == k1 || j == k2 || j == k3) && (p > kThresh);
            row[j] = keep ? p : 0.f;
        }
    }
    __syncthreads();

    // ================= Phase C: symmetrize + contiguous coalesced store ========================
    float* ob = out + (size_t)gt0 * (kN * kN);
    for (int q = tid; q < TILES * kN * kN; q += BDIM) {
        const int tt = q / (kN * kN);
        const int r  = q - tt * (kN * kN);
        const int i  = r / kN;
        const int j  = r - i * kN;
        const float v = 0.5f * (sBuf[tt * TSTR + i * RPAD + j] +
                                sBuf[tt * TSTR + j * RPAD + i]);
        ob[q] = v;   // block writes one contiguous 32*361-float span
    }
}

} // namespace

extern "C" void kernel_launch(void* const* d_in, const int* in_sizes, int n_in,
                              void* d_out, int out_size, void* d_ws, size_t ws_size,
                              hipStream_t stream)
{
    const float* feat = (const float*)d_in[0];
    float* out = (float*)d_out;
    dim3 grid((kB * kT) / TILES);   // 2048 blocks, exact
    dim3 block(BDIM);               // 320 threads
    hipLaunchKernelGGL(fused_graph_kernel, grid, block, 0, stream, feat, out);
}

// Round 2
// 1160.430 us; speedup vs baseline: 1.5486x; 1.5486x over previous
//
#include <hip/hip_runtime.h>
#include <math.h>

namespace {

constexpr int kB = 32;
constexpr int kN = 19;
constexpr int kT = 2048;
constexpr int kD = 128;

constexpr int TILES = 32;          // (b,t) tiles per block; 2048 blocks exactly, never crosses b
constexpr int TPT   = 10;          // threads per tile: upper-tri of a 4x4 grid of 5x5 blocks
constexpr int BDIM  = TILES * TPT; // 320 threads = 5 waves
constexpr int RPAD  = 21;          // odd G-row pitch -> conflict-light LDS
constexpr int TSTR  = 400;         // 19*21=399 -> 400 for alignment

constexpr float kTempInv = 10.0f;  // 1/TEMPERATURE
constexpr float kThresh  = 1e-4f;

// __launch_bounds__(320,2): 5-wave block; min 2 waves/EU = 2 blocks/CU floor ->
// VGPR cap ~200, room for acc[25]+ra/cb[40]+pointers with NO spills.
// (Round 1's (320,4) forced a ~102-reg budget -> 64-reg tier -> 1.9 GB of
// scratch spill traffic. Never again.)
__global__ __launch_bounds__(BDIM, 2)
void fused_graph_kernel(const float* __restrict__ feat, float* __restrict__ out)
{
    // 51.2 KB: per-tile G (Gram -> probs) matrices, pitch 21
    __shared__ float sG[TILES * TSTR];
    // 2.56 KB: per-tile inverse norms
    __shared__ float sInv[TILES * 20];

    const int tid = threadIdx.x;
    const int tl  = tid / TPT;        // tile-local index 0..31
    const int sub = tid - tl * TPT;   // 0..9 -> (bi,bj), bi<=bj
    const int bi    = (sub >= 4) + (sub >= 7) + (sub >= 9);
    const int start = bi * 4 - (bi * (bi - 1)) / 2;
    const int bj    = bi + (sub - start);

    const int gt0 = blockIdx.x * TILES;      // global tile base = b*T + t
    const int b0  = gt0 >> 11;               // /2048
    const int t0  = gt0 & (kT - 1);
    // feature element (b,n,t,d) at ((b*kN+n)*kT + t)*kD + d
    const float* tb = feat + ((size_t)b0 * kN * kT + (size_t)(t0 + tl)) * kD;

    // Row pointers for my 5x5 block (row 19 clamped to 18; garbage acc unused)
    const float* pa[5];
    const float* pb[5];
#pragma unroll
    for (int r = 0; r < 5; ++r) {
        int ar = bi * 5 + r; if (ar > kN - 1) ar = kN - 1;
        pa[r] = tb + (size_t)ar * (kT * kD);
    }
#pragma unroll
    for (int c = 0; c < 5; ++c) {
        int bc = bj * 5 + c; if (bc > kN - 1) bc = kN - 1;
        pb[c] = tb + (size_t)bc * (kT * kD);
    }

    float acc[5][5];
#pragma unroll
    for (int r = 0; r < 5; ++r)
#pragma unroll
        for (int c = 0; c < 5; ++c) acc[r][c] = 0.f;

    // ============ Phase A: direct-from-global 5x5 register-blocked Gram ============
    // Redundant row reads across the tile's 10 threads hit identical L2 lines in
    // the same instant -> HBM sees the input once. No LDS, no staging, no spills.
    for (int k = 0; k < kD; k += 4) {
        float4 ra[5], cb[5];
#pragma unroll
        for (int r = 0; r < 5; ++r)
            ra[r] = *(const float4*)(pa[r] + k);
        if (bi == bj) {
#pragma unroll
            for (int c = 0; c < 5; ++c) cb[c] = ra[c];
        } else {
#pragma unroll
            for (int c = 0; c < 5; ++c)
                cb[c] = *(const float4*)(pb[c] + k);
        }
#pragma unroll
        for (int r = 0; r < 5; ++r)
#pragma unroll
            for (int c = 0; c < 5; ++c) {
                acc[r][c] = fmaf(ra[r].x, cb[c].x, acc[r][c]);
                acc[r][c] = fmaf(ra[r].y, cb[c].y, acc[r][c]);
                acc[r][c] = fmaf(ra[r].z, cb[c].z, acc[r][c]);
                acc[r][c] = fmaf(ra[r].w, cb[c].w, acc[r][c]);
            }
    }

    // ============ Phase A2: scatter Gram into LDS with symmetric mirror ============
    {
        float* g = &sG[tl * TSTR];
#pragma unroll
        for (int r = 0; r < 5; ++r) {
            const int i = bi * 5 + r;
#pragma unroll
            for (int c = 0; c < 5; ++c) {
                const int j = bj * 5 + c;
                if (i < kN && j < kN) {
                    g[i * RPAD + j] = acc[r][c];
                    if (i != j) g[j * RPAD + i] = acc[r][c];
                }
            }
        }
    }
    __syncthreads();

    // ============ Phase B1: inverse norms from Gram diagonal ============
    for (int q = tid; q < TILES * kN; q += BDIM) {
        const int tt = q / kN;
        const int i  = q - tt * kN;
        const float nrm = sqrtf(sG[tt * TSTR + i * RPAD + i]);
        sInv[tt * 20 + i] = 1.0f / fmaxf(nrm, 1e-12f);
    }
    __syncthreads();

    // ============ Phase B2: per-row softmax + exact top-3 + threshold (in place) ============
    for (int q = tid; q < TILES * kN; q += BDIM) {
        const int tt = q / kN;
        const int i  = q - tt * kN;
        float* row = &sG[tt * TSTR + i * RPAD];
        const float* invp = &sInv[tt * 20];
        const float si = invp[i] * kTempInv;

        float l[kN];
        float m = -3.0e38f;
#pragma unroll
        for (int j = 0; j < kN; ++j) {
            const float g = row[j] * si * invp[j];
            l[j] = g;
            m = fmaxf(m, g);
        }
        float ssum = 0.f;
#pragma unroll
        for (int j = 0; j < kN; ++j) {
            const float e = __expf(l[j] - m);
            l[j] = e;
            ssum += e;
        }
        const float rs = 1.0f / ssum;
#pragma unroll
        for (int j = 0; j < kN; ++j) l[j] *= rs;

        // top-3 with lax.top_k tie semantics (strict > keeps lowest index on ties)
        int k1 = 0; float v1 = -1.f;
#pragma unroll
        for (int j = 0; j < kN; ++j) if (l[j] > v1) { v1 = l[j]; k1 = j; }
        int k2 = -1; float v2 = -1.f;
#pragma unroll
        for (int j = 0; j < kN; ++j) if (j != k1 && l[j] > v2) { v2 = l[j]; k2 = j; }
        int k3 = -1; float v3 = -1.f;
#pragma unroll
        for (int j = 0; j < kN; ++j) if (j != k1 && j != k2 && l[j] > v3) { v3 = l[j]; k3 = j; }

#pragma unroll
        for (int j = 0; j < kN; ++j) {
            const float p = l[j];
            const bool keep = (j == k1 || j == k2 || j == k3) && (p > kThresh);
            row[j] = keep ? p : 0.f;
        }
    }
    __syncthreads();

    // ============ Phase C: symmetrize + contiguous coalesced store ============
    float* ob = out + (size_t)gt0 * (kN * kN);
    for (int q = tid; q < TILES * kN * kN; q += BDIM) {
        const int tt = q / (kN * kN);
        const int r  = q - tt * (kN * kN);
        const int i  = r / kN;
        const int j  = r - i * kN;
        const float v = 0.5f * (sG[tt * TSTR + i * RPAD + j] +
                                sG[tt * TSTR + j * RPAD + i]);
        ob[q] = v;   // one contiguous 32*361-float span per block
    }
}

} // namespace

extern "C" void kernel_launch(void* const* d_in, const int* in_sizes, int n_in,
                              void* d_out, int out_size, void* d_ws, size_t ws_size,
                              hipStream_t stream)
{
    const float* feat = (const float*)d_in[0];
    float* out = (float*)d_out;
    dim3 grid((kB * kT) / TILES);   // 2048 blocks, exact
    dim3 block(BDIM);               // 320 threads
    hipLaunchKernelGGL(fused_graph_kernel, grid, block, 0, stream, feat, out);
}

// Round 3
// 1062.287 us; speedup vs baseline: 1.6917x; 1.0924x over previous
//
#include <hip/hip_runtime.h>
#include <math.h>

namespace {

constexpr int kB = 32;
constexpr int kN = 19;
constexpr int kT = 2048;
constexpr int kD = 128;

constexpr int TILES = 32;          // (b,t) tiles per block; 2048 blocks exactly, never crosses b
constexpr int TPT   = 10;          // threads per tile: upper-tri of a 4x4 grid of 5x5 blocks
constexpr int BDIM  = TILES * TPT; // 320 threads = 5 waves
constexpr int KC    = 16;          // k-chunk depth (floats per staging round)
constexpr int SROW  = kN * KC;     // stage tile stride = 304 floats
constexpr int CHUNK_F4 = TILES * kN * (KC / 4); // 2432 float4 per chunk

constexpr int RPAD  = 21;          // odd G-row pitch -> conflict-light LDS
constexpr int TSTR  = 400;         // 19*21=399 -> 400

constexpr float kTempInv = 10.0f;  // 1/TEMPERATURE
constexpr float kThresh  = 1e-4f;

// (320,2): 5-wave block, per-wave VGPR cap ~204 -> no spill tier (round 1's
// (320,4) forced 64 regs and 1.9 GB of scratch traffic). LDS (53,760 B) is the
// real occupancy cap: 3 blocks/CU = 161,280 B <= 163,840 B -> 15 waves/CU.
__global__ __launch_bounds__(BDIM, 2)
void fused_graph_kernel(const float* __restrict__ feat, float* __restrict__ out)
{
    // Union: Phase A staging [32][19][16] floats (38,912 B) then reused as
    // the per-tile Gram/prob matrices [32][19 x pitch 21] (51,200 B).
    __shared__ float smem[TILES * TSTR];
    __shared__ float sInv[TILES * 20];   // 2,560 B

    const int tid = threadIdx.x;
    const int tl  = tid / TPT;        // tile-local index 0..31
    const int sub = tid - tl * TPT;   // 0..9 -> (bi,bj), bi<=bj
    const int bi    = (sub >= 4) + (sub >= 7) + (sub >= 9);
    const int start = bi * 4 - (bi * (bi - 1)) / 2;
    const int bj    = bi + (sub - start);

    const int gt0 = blockIdx.x * TILES;      // global tile base = b*T + t
    const int b0  = gt0 >> 11;               // /2048
    const int t0  = gt0 & (kT - 1);

    // feat element (b,n,t,d) at ((b*kN+n)*kT + t)*kD + d ; kT*kD = 2^18, kD = 2^7
    const float* blkBase = feat + ((size_t)b0 * kN * kT + (size_t)t0) * kD;

    // clamped row indices for my 5x5 block (row 19 -> 18; garbage acc never used)
    int ar[5], bc[5];
#pragma unroll
    for (int r = 0; r < 5; ++r) { ar[r] = bi * 5 + r; if (ar[r] > kN - 1) ar[r] = kN - 1; }
#pragma unroll
    for (int c = 0; c < 5; ++c) { bc[c] = bj * 5 + c; if (bc[c] > kN - 1) bc[c] = kN - 1; }

    float acc[5][5];
#pragma unroll
    for (int r = 0; r < 5; ++r)
#pragma unroll
        for (int c = 0; c < 5; ++c) acc[r][c] = 0.f;

    // ============ Phase A: coalesced k-chunked staging + 5x5 register-blocked Gram ============
    for (int kc = 0; kc < kD; kc += KC) {
        // stage 32 tiles x 19 rows x 16 floats. q -> (d4,t,n): 4 consecutive
        // lanes cover one 64 B contiguous run; 16 runs per wave-load.
        for (int q = tid; q < CHUNK_F4; q += BDIM) {
            const int d4 = q & 3;
            const int t  = (q >> 2) & (TILES - 1);
            const int n  = q >> 7;
            const float4 v = *(const float4*)(blkBase + ((size_t)n << 18) + ((size_t)t << 7) + kc + d4 * 4);
            *(float4*)(&smem[t * SROW + n * KC + d4 * 4]) = v;
        }
        __syncthreads();

        const float* base = &smem[tl * SROW];
#pragma unroll
        for (int s0 = 0; s0 < 4; ++s0) {
            const int s = (s0 + sub) & 3;   // stagger to spread LDS banks
            float4 ra[5], cb[5];
#pragma unroll
            for (int r = 0; r < 5; ++r)
                ra[r] = *(const float4*)(base + ar[r] * KC + s * 4);
            if (bi == bj) {
#pragma unroll
                for (int c = 0; c < 5; ++c) cb[c] = ra[c];
            } else {
#pragma unroll
                for (int c = 0; c < 5; ++c)
                    cb[c] = *(const float4*)(base + bc[c] * KC + s * 4);
            }
#pragma unroll
            for (int r = 0; r < 5; ++r)
#pragma unroll
                for (int c = 0; c < 5; ++c) {
                    acc[r][c] = fmaf(ra[r].x, cb[c].x, acc[r][c]);
                    acc[r][c] = fmaf(ra[r].y, cb[c].y, acc[r][c]);
                    acc[r][c] = fmaf(ra[r].z, cb[c].z, acc[r][c]);
                    acc[r][c] = fmaf(ra[r].w, cb[c].w, acc[r][c]);
                }
        }
        __syncthreads();
    }

    // ============ Phase A2: scatter Gram into LDS (overwrites staging) with mirror ============
    {
        float* g = &smem[tl * TSTR];
#pragma unroll
        for (int r = 0; r < 5; ++r) {
            const int i = bi * 5 + r;
#pragma unroll
            for (int c = 0; c < 5; ++c) {
                const int j = bj * 5 + c;
                if (i < kN && j < kN) {
                    g[i * RPAD + j] = acc[r][c];
                    if (i != j) g[j * RPAD + i] = acc[r][c];
                }
            }
        }
    }
    __syncthreads();

    // ============ Phase B1: inverse norms from Gram diagonal ============
    for (int q = tid; q < TILES * kN; q += BDIM) {
        const int tt = q / kN;
        const int i  = q - tt * kN;
        const float nrm = sqrtf(smem[tt * TSTR + i * RPAD + i]);
        sInv[tt * 20 + i] = 1.0f / fmaxf(nrm, 1e-12f);
    }
    __syncthreads();

    // ============ Phase B2: per-row softmax + exact top-3 + threshold (in place) ============
    for (int q = tid; q < TILES * kN; q += BDIM) {
        const int tt = q / kN;
        const int i  = q - tt * kN;
        float* row = &smem[tt * TSTR + i * RPAD];
        const float* invp = &sInv[tt * 20];
        const float si = invp[i] * kTempInv;

        float l[kN];
        float m = -3.0e38f;
#pragma unroll
        for (int j = 0; j < kN; ++j) {
            const float g = row[j] * si * invp[j];
            l[j] = g;
            m = fmaxf(m, g);
        }
        float ssum = 0.f;
#pragma unroll
        for (int j = 0; j < kN; ++j) {
            const float e = __expf(l[j] - m);
            l[j] = e;
            ssum += e;
        }
        const float rs = 1.0f / ssum;
#pragma unroll
        for (int j = 0; j < kN; ++j) l[j] *= rs;

        // top-3 with lax.top_k tie semantics (strict > keeps lowest index on ties)
        int k1 = 0; float v1 = -1.f;
#pragma unroll
        for (int j = 0; j < kN; ++j) if (l[j] > v1) { v1 = l[j]; k1 = j; }
        int k2 = -1; float v2 = -1.f;
#pragma unroll
        for (int j = 0; j < kN; ++j) if (j != k1 && l[j] > v2) { v2 = l[j]; k2 = j; }
        int k3 = -1; float v3 = -1.f;
#pragma unroll
        for (int j = 0; j < kN; ++j) if (j != k1 && j != k2 && l[j] > v3) { v3 = l[j]; k3 = j; }

#pragma unroll
        for (int j = 0; j < kN; ++j) {
            const float p = l[j];
            const bool keep = (j == k1 || j == k2 || j == k3) && (p > kThresh);
            row[j] = keep ? p : 0.f;
        }
    }
    __syncthreads();

    // ============ Phase C: symmetrize + contiguous coalesced store ============
    float* ob = out + (size_t)gt0 * (kN * kN);
    for (int q = tid; q < TILES * kN * kN; q += BDIM) {
        const int tt = q / (kN * kN);
        const int r  = q - tt * (kN * kN);
        const int i  = r / kN;
        const int j  = r - i * kN;
        const float v = 0.5f * (smem[tt * TSTR + i * RPAD + j] +
                                smem[tt * TSTR + j * RPAD + i]);
        ob[q] = v;   // one contiguous 32*361-float span per block
    }
}

} // namespace

extern "C" void kernel_launch(void* const* d_in, const int* in_sizes, int n_in,
                              void* d_out, int out_size, void* d_ws, size_t ws_size,
                              hipStream_t stream)
{
    const float* feat = (const float*)d_in[0];
    float* out = (float*)d_out;
    dim3 grid((kB * kT) / TILES);   // 2048 blocks, exact
    dim3 block(BDIM);               // 320 threads
    hipLaunchKernelGGL(fused_graph_kernel, grid, block, 0, stream, feat, out);
}